// Round 12
// baseline (401.393 us; speedup 1.0000x reference)
//
#include <hip/hip_runtime.h>

// 2-layer LSTM (H=12), B=8192, T=1024 + 64 free-running steps.
// R18: R17 shell (4-wave/2-chain/1-block-per-CU, lgkm-only barrier, best 284us
// @68.6% busy, product 195 us-chip) + two gap/chain cuts:
// (1) x FOLDED INTO MFMA K-PADS: B k=3/11/19 = {xhi,xlo,xhi}, A = {whi,whi,
//     wlo} (hi/lo f16 splits) -> w_ih1*x computed inside the MFMA to f32
//     accuracy (residual wlo*xlo ~1e-6). Removes 12 chain-side fmafs.
// (2) PRODUCER COMPUTES Dh1 = A2|h1 * h1(t) + C2 right after act3 (3 MFMAs of
//     INDEPENDENT work placed in the producer's ~196cy dependency gap) and
//     ships v4f x3 through a fat FIFO; consumer's MFMA = A2|h2 * h2pack with
//     C-input = Dh1 (prefetched). Same math, 1-ulp reassociation.
// Cadence 8, depth-16 fat FIFO: iter kb writes slots kb..kb+7 (mod 16),
// reads kb-8..kb-1 — disjoint halves, every RAW/WAR pair separated by one
// barrier. absmax canary ~2.441e-4.
//
// Layout (harness-verified): row R=4v+q; chunk c row m=n -> v=4c+(m>>2),
// q=m&3, storage row q*12+v. K: k=8*(u%4)+(u/4), h1 at j<3, h2 at j+4.
// Fragments: A[m=lane&15][k=8g+j], B[k=8g+j][n=lane&15], D[4g+r][n].

typedef _Float16 v8h  __attribute__((ext_vector_type(8)));
typedef float    v4f  __attribute__((ext_vector_type(4)));

constexpr int T   = 1024;
constexpr int FUT = 64;
constexpr int TT  = T + FUT;   // 1088
constexpr int B   = 8192;

static __device__ __forceinline__ float fexp2(float x){ return __builtin_amdgcn_exp2f(x); }
static __device__ __forceinline__ float frcp (float x){ return __builtin_amdgcn_rcpf(x); }

static __device__ __forceinline__ void lgkm_barrier() {
  asm volatile("s_waitcnt lgkmcnt(0)\n\ts_barrier" ::: "memory");
}

__global__ __launch_bounds__(256) void lstm_r18_kernel(
    const float* __restrict__ input,
    const float* __restrict__ w_ih1, const float* __restrict__ w_hh1,
    const float* __restrict__ b_ih1, const float* __restrict__ b_hh1,
    const float* __restrict__ w_ih2, const float* __restrict__ w_hh2,
    const float* __restrict__ b_ih2, const float* __restrict__ b_hh2,
    const float* __restrict__ w_lin, const float* __restrict__ b_lin,
    float* __restrict__ out)
{
  const int tid  = threadIdx.x;
  const int wid  = tid >> 6;        // 0..3
  const int ch   = wid >> 1;        // chain within block (0/1)
  const int cw   = wid & 1;         // 0 = cell1 producer, 1 = cell2 consumer
  const int lane = tid & 63;
  const int g    = lane >> 4;
  const int n    = lane & 15;
  const int e0   = blockIdx.x * 32 + ch * 16;

  const float L2E = 1.4426950408889634f;
  const float sc[4] = { -L2E, -L2E, 2.0f * L2E, -L2E };  // i,f,g,o prescale
  const float TWO_L2E = 2.885390081777927f;

  // ---- fragments ---------------------------------------------------------
  // producer: A1 (w_hh1 + x-split pads), A2h1 (w_ih2, j<3 only), C1, C2
  // consumer: A2h2 (w_hh2, j+4 only), wl
  v8h Aw[3];     // producer: A1; consumer: A2h2
  v8h A2h1[3];   // producer only
  v4f Cw[3];     // producer: C1 (own MFMA C-input)
  v4f C2r[3];    // producer only: C2 (Dh1 C-input)
  float wl[3] = {0,0,0};
  {
    const int q = n & 3;
    #pragma unroll
    for (int c = 0; c < 3; ++c) {
      const int v   = 4 * c + (n >> 2);
      const int row = q * 12 + v;
      v8h a = {0,0,0,0,0,0,0,0}, a2 = {0,0,0,0,0,0,0,0};
      if (cw == 0) {
        #pragma unroll
        for (int j = 0; j < 3; ++j) {
          const int u = 4 * j + g;
          a[j]  = (_Float16)(sc[q] * w_hh1[row * 12 + u]);   // cell1 h1 cols
          a2[j] = (_Float16)(sc[q] * w_ih2[row * 12 + u]);   // Dh1: h1 cols
        }
        // x-split pad: k=3 (g0) whi*xhi, k=11 (g1) whi*xlo, k=19 (g2) wlo*xhi
        const float wfull = sc[q] * w_ih1[row];   // w_ih1 is [48,1]
        const _Float16 whi = (_Float16)wfull;
        const _Float16 wlo = (_Float16)(wfull - (float)whi);
        a[3] = (g == 0 || g == 1) ? whi : (g == 2 ? wlo : (_Float16)0);
      } else {
        #pragma unroll
        for (int j = 0; j < 3; ++j)
          a2[j + 4] = (_Float16)(sc[q] * w_hh2[row * 12 + (4 * j + g)]);
        a = a2;   // consumer Aw = A2h2
      }
      if (cw == 0) { Aw[c] = a; A2h1[c] = a2; }
      else         { Aw[c] = a; }
    }
    #pragma unroll
    for (int c = 0; c < 3; ++c) {
      const int v = 4 * c + g;
      #pragma unroll
      for (int r = 0; r < 4; ++r) {
        if (cw == 0) {
          Cw[c][r]  = sc[r] * (b_ih1[r * 12 + v] + b_hh1[r * 12 + v]);
          C2r[c][r] = sc[r] * (b_ih2[r * 12 + v] + b_hh2[r * 12 + v]);
        } else {
          Cw[c][r]  = 0.0f; C2r[c][r] = 0.0f;
        }
      }
      if (cw == 1) wl[c] = w_lin[v];
    }
  }
  const float blin = b_lin[0];

  // ---- LDS: fat Dh1 FIFO (96 KiB) + y-partials (8 KiB) -------------------
  __shared__ v4f  fifoD[2][16][3][64];   // [ch][slot][chunk][lane]
  __shared__ float yP[2][16][4][16];     // [ch][s%16][g][n]

  // ---- per-wave recurrent state ------------------------------------------
  float csw[3] = {0,0,0};                // pre-scaled by 2*log2e
  v8h  Bw = {0,0,0,0,0,0,0,0};

  const float* xrow = input + (size_t)(e0 + n) * T;
  float*       yrow = out   + (size_t)(e0 + n) * TT;
  const float  xl   = xrow[T - 1];

  auto act3 = [&](const float (&G)[3][4], float (&h)[3]) {
    float Ai[3], Af[3], Eg[3], Ao[3];
    #pragma unroll
    for (int c = 0; c < 3; ++c) Ai[c] = fexp2(G[c][0]);
    #pragma unroll
    for (int c = 0; c < 3; ++c) Af[c] = fexp2(G[c][1]);
    #pragma unroll
    for (int c = 0; c < 3; ++c) Eg[c] = fexp2(G[c][2]);
    #pragma unroll
    for (int c = 0; c < 3; ++c) Ao[c] = fexp2(G[c][3]);
    float pfx[3], P[3], R[3], T2[3], Nn[3], Ec[3], R2[3];
    #pragma unroll
    for (int c = 0; c < 3; ++c) { pfx[c] = 1.0f + Af[c]; P[c] = (1.0f + Ai[c]) * (1.0f + Eg[c]); }
    #pragma unroll
    for (int c = 0; c < 3; ++c) R[c]  = frcp(P[c] * pfx[c]);
    #pragma unroll
    for (int c = 0; c < 3; ++c) T2[c] = fmaf(Eg[c], TWO_L2E, -TWO_L2E) * pfx[c];
    #pragma unroll
    for (int c = 0; c < 3; ++c) Nn[c] = fmaf(csw[c], P[c], T2[c]);
    #pragma unroll
    for (int c = 0; c < 3; ++c) csw[c] = Nn[c] * R[c];
    #pragma unroll
    for (int c = 0; c < 3; ++c) Ec[c] = fexp2(csw[c]);
    #pragma unroll
    for (int c = 0; c < 3; ++c) R2[c] = frcp((1.0f + Ao[c]) * (1.0f + Ec[c]));
    #pragma unroll
    for (int c = 0; c < 3; ++c) h[c] = (Ec[c] - 1.0f) * R2[c];
  };

  // producer: cell1 step t (x inside MFMA) + Dh1 MFMAs + fat-FIFO write
  auto stepA = [&](int t, float xs) {
    // x-split pad value for this lane (independent of chain; hoistable)
    const _Float16 xh = (_Float16)xs;
    const _Float16 xo = (_Float16)(xs - (float)xh);
    Bw[3] = (g == 1) ? xo : ((g == 3) ? (_Float16)0 : xh);

    v4f D0 = __builtin_amdgcn_mfma_f32_16x16x32_f16(Aw[0], Bw, Cw[0], 0, 0, 0);
    v4f D1 = __builtin_amdgcn_mfma_f32_16x16x32_f16(Aw[1], Bw, Cw[1], 0, 0, 0);
    v4f D2 = __builtin_amdgcn_mfma_f32_16x16x32_f16(Aw[2], Bw, Cw[2], 0, 0, 0);
    float G[3][4], h[3];
    #pragma unroll
    for (int r = 0; r < 4; ++r) G[0][r] = D0[r];
    #pragma unroll
    for (int r = 0; r < 4; ++r) G[1][r] = D1[r];
    #pragma unroll
    for (int r = 0; r < 4; ++r) G[2][r] = D2[r];
    act3(G, h);
    Bw[0] = (_Float16)h[0]; Bw[1] = (_Float16)h[1]; Bw[2] = (_Float16)h[2];

    // Dh1(t) = A2|h1 * h1(t) + C2 — independent work, fills the act3 gap.
    // (Bw[3]=x pad and h2 slots hit zero A2h1 entries.)
    v4f P0 = __builtin_amdgcn_mfma_f32_16x16x32_f16(A2h1[0], Bw, C2r[0], 0, 0, 0);
    v4f P1 = __builtin_amdgcn_mfma_f32_16x16x32_f16(A2h1[1], Bw, C2r[1], 0, 0, 0);
    v4f P2 = __builtin_amdgcn_mfma_f32_16x16x32_f16(A2h1[2], Bw, C2r[2], 0, 0, 0);
    fifoD[ch][t & 15][0][lane] = P0;
    fifoD[ch][t & 15][1][lane] = P1;
    fifoD[ch][t & 15][2][lane] = P2;
  };

  // consumer: cell2 step s; C-input = prefetched Dh1
  auto stepB = [&](const v4f (&pd)[3], int s) {
    v4f E0 = __builtin_amdgcn_mfma_f32_16x16x32_f16(Aw[0], Bw, pd[0], 0, 0, 0);
    v4f E1 = __builtin_amdgcn_mfma_f32_16x16x32_f16(Aw[1], Bw, pd[1], 0, 0, 0);
    v4f E2 = __builtin_amdgcn_mfma_f32_16x16x32_f16(Aw[2], Bw, pd[2], 0, 0, 0);
    float G[3][4], h[3];
    #pragma unroll
    for (int r = 0; r < 4; ++r) G[0][r] = E0[r];
    #pragma unroll
    for (int r = 0; r < 4; ++r) G[1][r] = E1[r];
    #pragma unroll
    for (int r = 0; r < 4; ++r) G[2][r] = E2[r];
    act3(G, h);
    Bw[4] = (_Float16)h[0]; Bw[5] = (_Float16)h[1]; Bw[6] = (_Float16)h[2];
    float yp = h[0] * wl[0];
    yp = fmaf(h[1], wl[1], yp);
    yp = fmaf(h[2], wl[2], yp);
    yP[ch][s & 15][g][n] = yp;
  };

  auto flush = [&](int sbase) {
    const int tq = lane >> 4;
    float ys[4];
    #pragma unroll
    for (int ii = 0; ii < 4; ++ii) {
      const int j = 4 * tq + ii;
      ys[ii] = (yP[ch][j][0][n] + yP[ch][j][1][n])
             + (yP[ch][j][2][n] + yP[ch][j][3][n]) + blin;
    }
    *reinterpret_cast<float4*>(yrow + sbase + 4 * tq) =
        make_float4(ys[0], ys[1], ys[2], ys[3]);
  };

  // Prologue x: steps 0..7.
  float4 xc0 = make_float4(0,0,0,0), xc1 = xc0;
  if (cw == 0) {
    xc0 = *reinterpret_cast<const float4*>(xrow);
    xc1 = *reinterpret_cast<const float4*>(xrow + 4);
  }

  for (int kb = 0; kb <= TT; kb += 8) {
    if (cw == 0) {
      if (kb < TT) {
        float4 xn0, xn1;
        const int nb = kb + 8;
        if (nb < T) {
          xn0 = *reinterpret_cast<const float4*>(xrow + nb);
          xn1 = *reinterpret_cast<const float4*>(xrow + nb + 4);
        } else {
          xn0 = make_float4(xl, xl, xl, xl); xn1 = xn0;
        }
        stepA(kb + 0, xc0.x);
        stepA(kb + 1, xc0.y);
        stepA(kb + 2, xc0.z);
        stepA(kb + 3, xc0.w);
        stepA(kb + 4, xc1.x);
        stepA(kb + 5, xc1.y);
        stepA(kb + 6, xc1.z);
        stepA(kb + 7, xc1.w);
        xc0 = xn0; xc1 = xn1;
      }
    } else {
      if (kb >= 8) {
        const int s0 = kb - 8;
        // two 4-step prefetch batches (all slots one barrier old)
        v4f pd[4][3];
        #pragma unroll
        for (int s = 0; s < 4; ++s)
          #pragma unroll
          for (int c = 0; c < 3; ++c)
            pd[s][c] = fifoD[ch][(s0 + s) & 15][c][lane];
        #pragma unroll
        for (int s = 0; s < 4; ++s) stepB(pd[s], s0 + s);
        #pragma unroll
        for (int s = 0; s < 4; ++s)
          #pragma unroll
          for (int c = 0; c < 3; ++c)
            pd[s][c] = fifoD[ch][(s0 + 4 + s) & 15][c][lane];
        #pragma unroll
        for (int s = 0; s < 4; ++s) stepB(pd[s], s0 + 4 + s);
        if ((kb & 15) == 0) flush(kb - 16);
      }
    }
    lgkm_barrier();
  }
}

extern "C" void kernel_launch(void* const* d_in, const int* in_sizes, int n_in,
                              void* d_out, int out_size, void* d_ws, size_t ws_size,
                              hipStream_t stream) {
  const float* input = (const float*)d_in[0];
  const float* w_ih1 = (const float*)d_in[2];
  const float* w_hh1 = (const float*)d_in[3];
  const float* b_ih1 = (const float*)d_in[4];
  const float* b_hh1 = (const float*)d_in[5];
  const float* w_ih2 = (const float*)d_in[6];
  const float* w_hh2 = (const float*)d_in[7];
  const float* b_ih2 = (const float*)d_in[8];
  const float* b_hh2 = (const float*)d_in[9];
  const float* w_lin = (const float*)d_in[10];
  const float* b_lin = (const float*)d_in[11];
  float* out = (float*)d_out;

  dim3 grid(B / 32);   // 256 blocks x 4 waves = 1024 waves, 1 block per CU
  dim3 block(256);
  hipLaunchKernelGGL(lstm_r18_kernel, grid, block, 0, stream,
                     input, w_ih1, w_hh1, b_ih1, b_hh1,
                     w_ih2, w_hh2, b_ih2, b_hh2, w_lin, b_lin, out);
}